// Round 10
// baseline (7594.492 us; speedup 1.0000x reference)
//
#include <hip/hip_runtime.h>
#include <hip/hip_bf16.h>
#include <hip/hip_cooperative_groups.h>

// MAGCRN on MI355X — round 9: MFMA gconv with coalesced (transposed) weights.
//  * Round-9 counters: coop recurrence moved ~1GB/dispatch at 250 GB/s — the
//    gconv weight loads were 32-lane broadcasts (32 useful B per wave-instr).
//  * gconv is now a per-node MFMA GEMM: weights stored transposed [o][kc]
//    (padded to KCP), B-fragments are contiguous dwordx4 (1KB/wave-instr);
//    A staged in LDS bf16 [32][KCP+8].
//  * Coop grid sized via occupancy query (512 if 2 blocks/CU, else 256);
//    kernel adapts via gridDim; failed launch -> per-phase fallback.

namespace cg = cooperative_groups;

using bf16 = __hip_bfloat16;
#define B2F(x) __bfloat162float(x)

#define NN 512
#define BBATCH 32
#define HHID 64
#define TT 12
#define EE 16

typedef __attribute__((ext_vector_type(4))) float f32x4;
typedef __attribute__((ext_vector_type(8))) short bf16x8;

__device__ inline float wsum(float x) {
#pragma unroll
  for (int off = 32; off > 0; off >>= 1) x += __shfl_xor(x, off, 64);
  return x;
}
__device__ inline void storev(float* p, float v) { *p = v; }
__device__ inline void storev(bf16* p, float v) { *p = __float2bfloat16(v); }

__global__ __launch_bounds__(256) void zero_f32_kernel(float* __restrict__ p, int n) {
  int i = blockIdx.x * 256 + threadIdx.x;
  if (i < n) p[i] = 0.0f;
}

// ---------------- setup kernels ----------------

__global__ __launch_bounds__(256) void adj_kernel(const float* __restrict__ emb,
                                                  bf16* __restrict__ adjb) {
  __shared__ float embAll[NN * EE];
  __shared__ float red[256];
  int tid = threadIdx.x, n = blockIdx.x;
  for (int i = tid; i < NN * EE; i += 256) embAll[i] = emb[i];
  __syncthreads();
  float v[2];
#pragma unroll
  for (int j = 0; j < 2; j++) {
    int m = tid + j * 256;
    float s = 0.f;
#pragma unroll
    for (int e = 0; e < EE; e++) s += embAll[n * EE + e] * embAll[m * EE + e];
    v[j] = fmaxf(s, 0.0f);
  }
  float mx = fmaxf(v[0], v[1]);
  red[tid] = mx; __syncthreads();
  for (int s = 128; s > 0; s >>= 1) { if (tid < s) red[tid] = fmaxf(red[tid], red[tid + s]); __syncthreads(); }
  mx = red[0]; __syncthreads();
  float e0 = expf(v[0] - mx), e1 = expf(v[1] - mx);
  red[tid] = e0 + e1; __syncthreads();
  for (int s = 128; s > 0; s >>= 1) { if (tid < s) red[tid] += red[tid + s]; __syncthreads(); }
  float inv = 1.0f / red[0];
  adjb[n * NN + tid] = __float2bfloat16(e0 * inv);
  adjb[n * NN + tid + 256] = __float2bfloat16(e1 * inv);
}

// bias generator (small): out[n][j] = sum_e emb[n][e] * pool[e][j]
__global__ __launch_bounds__(256) void wgen_kernel(const float* __restrict__ pool,
                                                   const float* __restrict__ emb,
                                                   float* __restrict__ out, int J) {
  __shared__ float embL[128 * EE];
  int tid = threadIdx.x;
  int n0 = blockIdx.y * 128;
  for (int i = tid; i < 128 * EE; i += 256) embL[i] = emb[n0 * EE + i];
  __syncthreads();
  int j = blockIdx.x * 256 + tid;
  if (j >= J) return;
  float pw[EE];
#pragma unroll
  for (int e = 0; e < EE; e++) pw[e] = pool[e * J + j];
#pragma unroll 4
  for (int nn = 0; nn < 128; nn++) {
    float s = 0.f;
#pragma unroll
    for (int e = 0; e < EE; e++) s += embL[nn * EE + e] * pw[e];
    out[(size_t)(n0 + nn) * J + j] = s;
  }
}

// transposed weight generator: out[n][o*KCP + kc] = sum_e emb[n][e]*pool[e][j],
// j = kc*O + o ; O is a power of two (lgO), J = KC*O (unpadded)
__global__ __launch_bounds__(256) void wgen_t_kernel(const float* __restrict__ pool,
                                                     const float* __restrict__ emb,
                                                     bf16* __restrict__ out, int J,
                                                     int lgO, int KCP) {
  __shared__ float embL[128 * EE];
  int tid = threadIdx.x;
  int n0 = blockIdx.y * 128;
  for (int i = tid; i < 128 * EE; i += 256) embL[i] = emb[n0 * EE + i];
  __syncthreads();
  int j = blockIdx.x * 256 + tid;
  if (j >= J) return;
  int O = 1 << lgO;
  int kc = j >> lgO, o = j & (O - 1);
  float pw[EE];
#pragma unroll
  for (int e = 0; e < EE; e++) pw[e] = pool[e * J + j];
  size_t SN = (size_t)KCP << lgO;
#pragma unroll 4
  for (int nn = 0; nn < 128; nn++) {
    float s = 0.f;
#pragma unroll
    for (int e = 0; e < EE; e++) s += embL[nn * EE + e] * pw[e];
    out[(size_t)(n0 + nn) * SN + (size_t)o * KCP + kc] = __float2bfloat16(s);
  }
}

__global__ __launch_bounds__(256) void pw_kernel(const float* __restrict__ upool,
                                                 const float* __restrict__ hypW,
                                                 float* __restrict__ PW) {
  __shared__ float red[256];
  int j = blockIdx.x, e = blockIdx.y, tid = threadIdx.x;
  float s = 0.f;
#pragma unroll 4
  for (int p = tid; p < 16384; p += 256) s += upool[e * 16384 + p] * hypW[p * 48 + j];
  red[tid] = s; __syncthreads();
  for (int t = 128; t > 0; t >>= 1) { if (tid < t) red[tid] += red[tid + t]; __syncthreads(); }
  if (tid == 0) PW[e * 48 + j] = red[0];
}

__global__ __launch_bounds__(256) void fs_kernel(const float* __restrict__ emb,
                                                 const float* __restrict__ PW,
                                                 const float* __restrict__ hypb,
                                                 float* __restrict__ fs) {
  int id = blockIdx.x * 256 + threadIdx.x;
  if (id >= NN * TT) return;
  int n = id / TT, t = id % TT;
  float s = 0.f;
#pragma unroll
  for (int f = 0; f < 4; f++) {
    int j = t * 4 + f;
    float h = hypb[j];
#pragma unroll
    for (int e = 0; e < EE; e++) h += emb[n * EE + e] * PW[e * 48 + j];
    s += h;
  }
  fs[id] = s;
}

__global__ __launch_bounds__(256) void cvt_src_kernel(const float* __restrict__ src,
                                                      bf16* __restrict__ x) {
  int id = blockIdx.x * 256 + threadIdx.x;  // < 393216
  int c = id & 1, b = (id >> 1) & 31, n = (id >> 6) & 511, t = id >> 15;
  x[id] = __float2bfloat16(src[((b * TT + t) * NN + n) * 2 + c]);
}

// ---------------- shared device functions ----------------

// One 64n x 64q diffusion tile via MFMA 16x16x32 (proven round-6/7 structure).
__device__ inline void diffuse_tile(const bf16* __restrict__ adjb,
                                    const bf16* __restrict__ X, bf16* __restrict__ Y,
                                    int Q, int n0, int q0, char* smraw, int tid) {
  constexpr int LP = 66;
  unsigned short* xs = (unsigned short*)smraw;  // [64][66]
  int w = tid >> 6, lane = tid & 63;
  int col = lane & 15, quad = lane >> 4;
  f32x4 acc[4];
#pragma unroll
  for (int ct = 0; ct < 4; ct++) acc[ct] = (f32x4){0.f, 0.f, 0.f, 0.f};
  const bf16* arow = adjb + (size_t)(n0 + w * 16 + col) * NN;
  for (int c = 0; c < 8; c++) {
    __syncthreads();
#pragma unroll
    for (int i0 = 0; i0 < 2; i0++) {
      int i = i0 * 256 + tid;
      int row = i >> 3, seg = i & 7;
      uint4 v = *(const uint4*)(X + (size_t)(c * 64 + row) * Q + q0 + seg * 8);
      unsigned int* dst = (unsigned int*)&xs[row * LP + seg * 8];
      dst[0] = v.x; dst[1] = v.y; dst[2] = v.z; dst[3] = v.w;
    }
    __syncthreads();
#pragma unroll
    for (int ki = 0; ki < 2; ki++) {
      bf16x8 a = *(const bf16x8*)(arow + c * 64 + ki * 32 + quad * 8);
#pragma unroll
      for (int ct = 0; ct < 4; ct++) {
        bf16x8 b;
#pragma unroll
        for (int j = 0; j < 8; j++)
          b[j] = (short)xs[(ki * 32 + quad * 8 + j) * LP + ct * 16 + col];
        acc[ct] = __builtin_amdgcn_mfma_f32_16x16x32_bf16(a, b, acc[ct], 0, 0, 0);
      }
    }
  }
#pragma unroll
  for (int ct = 0; ct < 4; ct++) {
#pragma unroll
    for (int r = 0; r < 4; r++) {
      int row = n0 + w * 16 + quad * 4 + r;
      Y[(size_t)row * Q + q0 + ct * 16 + col] = __float2bfloat16(acc[ct][r]);
    }
  }
}

// Stage A-operand (concat features, bf16) into LDS [32][KCP+8].
template <int C>
__device__ inline void stage_A(int n, int tid, unsigned short* xinb,
    const bf16* __restrict__ xt, const bf16* __restrict__ xd,
    const bf16* __restrict__ sa, const bf16* __restrict__ sad) {
  constexpr int cc = C + HHID, KC = 2 * cc, KCP = (KC + 31) & ~31, PIT = KCP + 8;
  __syncthreads();  // guard LDS reuse
  for (int i = tid; i < 32 * KCP; i += 256) {
    int b = i / KCP, kc = i - b * KCP;
    unsigned short v = 0;
    if (kc < C)            v = *(const unsigned short*)&xt[(n * 32 + b) * C + kc];
    else if (kc < cc)      v = *(const unsigned short*)&sa[(n * 32 + b) * HHID + kc - C];
    else if (kc < cc + C)  v = *(const unsigned short*)&xd[(n * 32 + b) * C + kc - cc];
    else if (kc < KC)      v = *(const unsigned short*)&sad[(n * 32 + b) * HHID + kc - cc - C];
    xinb[b * PIT + kc] = v;
  }
  __syncthreads();
}

// Gate gconv via MFMA: [32 x KC] @ Wt[128 x KCP]^T -> sigmoid -> zs/rbuf.
template <int C>
__device__ inline void gate_mfma(int n, int tid, const unsigned short* xinb,
    const bf16* __restrict__ gWt, const float* __restrict__ gb,
    const float* __restrict__ state, bf16* __restrict__ zs, bf16* __restrict__ rbuf) {
  constexpr int KC = 2 * (C + HHID), KCP = (KC + 31) & ~31, PIT = KCP + 8;
  int w = tid >> 6, lane = tid & 63, col = lane & 15, quad = lane >> 4;
  f32x4 acc[2][2];
#pragma unroll
  for (int i = 0; i < 2; i++)
#pragma unroll
    for (int mt = 0; mt < 2; mt++) acc[i][mt] = (f32x4){0.f, 0.f, 0.f, 0.f};
  const bf16* Wn = gWt + (size_t)n * KCP * 128;
#pragma unroll 2
  for (int k0 = 0; k0 < KCP; k0 += 32) {
    int ko = k0 + quad * 8;
    bf16x8 a0 = *(const bf16x8*)&xinb[col * PIT + ko];
    bf16x8 a1 = *(const bf16x8*)&xinb[(16 + col) * PIT + ko];
#pragma unroll
    for (int i = 0; i < 2; i++) {
      int o = (w + i * 4) * 16 + col;
      bf16x8 bf = *(const bf16x8*)(Wn + (size_t)o * KCP + ko);
      acc[i][0] = __builtin_amdgcn_mfma_f32_16x16x32_bf16(a0, bf, acc[i][0], 0, 0, 0);
      acc[i][1] = __builtin_amdgcn_mfma_f32_16x16x32_bf16(a1, bf, acc[i][1], 0, 0, 0);
    }
  }
#pragma unroll
  for (int i = 0; i < 2; i++) {
    int o = (w + i * 4) * 16 + col;
    float bv = gb[n * 128 + o];
#pragma unroll
    for (int mt = 0; mt < 2; mt++)
#pragma unroll
      for (int r = 0; r < 4; r++) {
        int m = mt * 16 + quad * 4 + r;
        float zr = 1.0f / (1.0f + expf(-(acc[i][mt][r] + bv)));
        int idx = (n * 32 + m) * HHID + (o & 63);
        if (o < HHID) zs[idx] = __float2bfloat16(zr * state[idx]);
        else          rbuf[idx] = __float2bfloat16(zr);
      }
  }
}

// Update gconv via MFMA: tanh -> h = r*state + (1-r)*hc -> state/sb/xout.
template <int C>
__device__ inline void upd_mfma(int n, int tid, const unsigned short* xinb,
    const bf16* __restrict__ uWt, const float* __restrict__ ub,
    float* __restrict__ state, bf16* __restrict__ sb,
    const bf16* __restrict__ rbuf, bf16* __restrict__ xo) {
  constexpr int KC = 2 * (C + HHID), KCP = (KC + 31) & ~31, PIT = KCP + 8;
  int w = tid >> 6, lane = tid & 63, col = lane & 15, quad = lane >> 4;
  f32x4 acc[2];
  acc[0] = (f32x4){0.f, 0.f, 0.f, 0.f};
  acc[1] = (f32x4){0.f, 0.f, 0.f, 0.f};
  const bf16* Wn = uWt + (size_t)n * KCP * 64;
  int o = w * 16 + col;
#pragma unroll 2
  for (int k0 = 0; k0 < KCP; k0 += 32) {
    int ko = k0 + quad * 8;
    bf16x8 a0 = *(const bf16x8*)&xinb[col * PIT + ko];
    bf16x8 a1 = *(const bf16x8*)&xinb[(16 + col) * PIT + ko];
    bf16x8 bf = *(const bf16x8*)(Wn + (size_t)o * KCP + ko);
    acc[0] = __builtin_amdgcn_mfma_f32_16x16x32_bf16(a0, bf, acc[0], 0, 0, 0);
    acc[1] = __builtin_amdgcn_mfma_f32_16x16x32_bf16(a1, bf, acc[1], 0, 0, 0);
  }
  float bv = ub[n * 64 + o];
#pragma unroll
  for (int mt = 0; mt < 2; mt++)
#pragma unroll
    for (int r = 0; r < 4; r++) {
      int m = mt * 16 + quad * 4 + r;
      int idx = (n * 32 + m) * HHID + o;
      float hc = tanhf(acc[mt][r] + bv);
      float rr = B2F(rbuf[idx]);
      float st = state[idx];
      float h = rr * st + (1.0f - rr) * hc;
      state[idx] = h;
      bf16 hb = __float2bfloat16(h);
      sb[idx] = hb;
      xo[idx] = hb;
    }
}

// ---------------- cooperative recurrence (gridDim-agnostic) ----------------

template <int C>
__global__ __launch_bounds__(256, 2) void recur_kernel(
    const bf16* __restrict__ adjb, const bf16* __restrict__ xin,
    const bf16* __restrict__ gWt, const float* __restrict__ gb,
    const bf16* __restrict__ uWt, const float* __restrict__ ub,
    float* __restrict__ state, bf16* __restrict__ sb,
    bf16* __restrict__ sdiff, bf16* __restrict__ zs, bf16* __restrict__ zsdiff,
    bf16* __restrict__ rbuf, bf16* __restrict__ xd, bf16* __restrict__ xout) {
  constexpr int KC = 2 * (C + HHID), KCP = (KC + 31) & ~31, PIT = KCP + 8;
  constexpr int QX = 32 * C;
  constexpr int SMB = (32 * PIT * 2 > 8448) ? 32 * PIT * 2 : 8448;
  __shared__ __align__(16) char smraw[SMB];
  unsigned short* xinb = (unsigned short*)smraw;
  cg::grid_group grid = cg::this_grid();
  int bid = blockIdx.x, tid = threadIdx.x, NB = gridDim.x;

  for (int i = bid * 256 + tid; i < NN * 32 * HHID; i += NB * 256) {
    state[i] = 0.f;
    sb[i] = __float2bfloat16(0.f);
  }
  if (C == 2) {  // layer0: all-t input diffusion (Q=64, 96 tiles)
    for (int tile = bid; tile < 96; tile += NB) {
      int t = tile >> 3, nn0 = (tile & 7) * 64;
      diffuse_tile(adjb, xin + (size_t)t * NN * QX, xd + (size_t)t * NN * QX,
                   QX, nn0, 0, smraw, tid);
    }
  }
  grid.sync();

  for (int t = 0; t < TT; t++) {
    const bf16* xt = xin + (size_t)t * NN * QX;
    const bf16* xdt = (C == 2) ? (xd + (size_t)t * NN * QX) : xd;
    bf16* xo = xout + (size_t)t * NN * 32 * HHID;
    // P1: sdiff = adj @ sb ; layer1 also xdiff = adj @ xt
    int TOT = (C == 64) ? 512 : 256;
    for (int tile = bid; tile < TOT; tile += NB) {
      if (tile < 256)
        diffuse_tile(adjb, sb, sdiff, 2048, (tile >> 5) * 64, (tile & 31) * 64, smraw, tid);
      else {
        int t2 = tile - 256;
        diffuse_tile(adjb, xt, xd, 2048, (t2 >> 5) * 64, (t2 & 31) * 64, smraw, tid);
      }
    }
    grid.sync();
    // P2: gate gconv (MFMA)
    for (int n = bid; n < NN; n += NB) {
      stage_A<C>(n, tid, xinb, xt, xdt, sb, sdiff);
      gate_mfma<C>(n, tid, xinb, gWt, gb, state, zs, rbuf);
    }
    grid.sync();
    // P3: zsdiff = adj @ zs
    for (int tile = bid; tile < 256; tile += NB)
      diffuse_tile(adjb, zs, zsdiff, 2048, (tile >> 5) * 64, (tile & 31) * 64, smraw, tid);
    grid.sync();
    // P4: update gconv (MFMA) -> state, sb, xout[t]
    for (int n = bid; n < NN; n += NB) {
      stage_A<C>(n, tid, xinb, xt, xdt, zs, zsdiff);
      upd_mfma<C>(n, tid, xinb, uWt, ub, state, sb, rbuf, xo);
    }
    grid.sync();
  }
}

// ---------------- fallback per-phase kernels (same device functions) --------

__global__ __launch_bounds__(256, 2) void diffuse0_kernel(const bf16* __restrict__ adjb,
                                                          const bf16* __restrict__ X,
                                                          bf16* __restrict__ Y) {
  __shared__ __align__(16) char smraw[8448];
  int bid = blockIdx.x;  // 96
  int t = bid >> 3, n0 = (bid & 7) * 64;
  diffuse_tile(adjb, X + (size_t)t * NN * 64, Y + (size_t)t * NN * 64, 64, n0, 0,
               smraw, threadIdx.x);
}

__global__ __launch_bounds__(256, 2) void diffuse1_kernel(const bf16* __restrict__ adjb,
                                                          const bf16* __restrict__ X,
                                                          bf16* __restrict__ Y) {
  __shared__ __align__(16) char smraw[8448];
  int bid = blockIdx.x;  // 256
  diffuse_tile(adjb, X, Y, 2048, (bid >> 5) * 64, (bid & 31) * 64, smraw, threadIdx.x);
}

template <int C>
__global__ __launch_bounds__(256, 2) void gate_wrap(
    const bf16* xt, const bf16* xdt, const bf16* sa, const bf16* sad,
    const bf16* gWt, const float* gb, const float* state, bf16* zs, bf16* rbuf) {
  constexpr int KC = 2 * (C + HHID), KCP = (KC + 31) & ~31, PIT = KCP + 8;
  __shared__ __align__(16) unsigned short xinb[32 * PIT];
  stage_A<C>(blockIdx.x, threadIdx.x, xinb, xt, xdt, sa, sad);
  gate_mfma<C>(blockIdx.x, threadIdx.x, xinb, gWt, gb, state, zs, rbuf);
}

template <int C>
__global__ __launch_bounds__(256, 2) void upd_wrap(
    const bf16* xt, const bf16* xdt, const bf16* sa, const bf16* sad,
    const bf16* uWt, const float* ub, float* state, bf16* sb,
    const bf16* rbuf, bf16* xo) {
  constexpr int KC = 2 * (C + HHID), KCP = (KC + 31) & ~31, PIT = KCP + 8;
  __shared__ __align__(16) unsigned short xinb[32 * PIT];
  stage_A<C>(blockIdx.x, threadIdx.x, xinb, xt, xdt, sa, sad);
  upd_mfma<C>(blockIdx.x, threadIdx.x, xinb, uWt, ub, state, sb, rbuf, xo);
}

// ---------------- epilogue kernels (unchanged, passing) ----------------

#define TP 68  // padded fp32 row stride (conflict-free)

__global__ __launch_bounds__(256, 4) void attn1_kernel(
    const bf16* __restrict__ x1, const float* __restrict__ fsb,
    const float* __restrict__ Wq, const float* __restrict__ bq,
    const float* __restrict__ Wk, const float* __restrict__ bk,
    const float* __restrict__ Wv, const float* __restrict__ bv,
    const float* __restrict__ ln1g, const float* __restrict__ ln1b,
    bf16* __restrict__ val) {
  __shared__ bf16 Wq_s[4096], Wk_s[4096], Wv_s[4096];
  __shared__ float X[TT * TP], qs[TT * TP], ks[TT * TP];
  __shared__ float A[2 * TT * TT];
  __shared__ float ovv[64], fss[TT];
  __shared__ float bqs[64], bks[64], bvs[64], g1s[64], b1s[64];
  int tid = threadIdx.x;
  for (int i = tid; i < 4096; i += 256) {
    Wq_s[i] = __float2bfloat16(Wq[i]);
    Wk_s[i] = __float2bfloat16(Wk[i]);
    Wv_s[i] = __float2bfloat16(Wv[i]);
  }
  if (tid < 64) {
    bqs[tid] = bq[tid]; bks[tid] = bk[tid]; bvs[tid] = bv[tid];
    g1s[tid] = ln1g[tid]; b1s[tid] = ln1b[tid];
  }
  __syncthreads();
  for (int g = 0; g < 8; g++) {
    int p = blockIdx.x * 8 + g;
    int b = p >> 9, n = p & 511;
    for (int i = tid; i < TT * 64; i += 256) {
      int t = i >> 6, j = i & 63;
      X[t * TP + j] = B2F(x1[(((size_t)t * NN + n) * BBATCH + b) * HHID + j]);
    }
    if (tid < TT) fss[tid] = fsb[n * TT + tid];
    __syncthreads();
    for (int i = tid; i < TT * 64; i += 256) {
      int t = i >> 6, h = i & 63;
      float aq = bqs[h], ak = bks[h];
#pragma unroll 8
      for (int j = 0; j < 64; j++) {
        float xv = X[t * TP + j];
        aq += xv * B2F(Wq_s[j * 64 + h]);
        ak += xv * B2F(Wk_s[j * 64 + h]);
      }
      qs[t * TP + h] = aq; ks[t * TP + h] = ak;
    }
    if (tid < 64) {
      float s = 0.f;
#pragma unroll 8
      for (int j = 0; j < 64; j++) s += X[11 * TP + j] * B2F(Wv_s[j * 64 + tid]);
      ovv[tid] = s;
    }
    __syncthreads();
    for (int i = tid; i < 2 * TT * TT; i += 256) {
      int hd = i / (TT * TT), ts = i % (TT * TT), t = ts / TT, s = ts % TT;
      float acc = 0.f;
#pragma unroll
      for (int d = 0; d < 32; d++) acc += qs[t * TP + hd * 32 + d] * ks[s * TP + hd * 32 + d];
      A[i] = acc * 0.17677669529663687f;
    }
    __syncthreads();
    if (tid < 2 * TT) {
      int hd = tid / TT, t = tid % TT;
      float* row = &A[hd * TT * TT + t * TT];
      float m = row[0];
      for (int s = 1; s < TT; s++) m = fmaxf(m, row[s]);
      float sm = 0.f;
      for (int s = 0; s < TT; s++) { float e = expf(row[s] - m); row[s] = e; sm += e; }
      float inv = 1.0f / sm;
      for (int s = 0; s < TT; s++) row[s] *= inv;
    }
    __syncthreads();
#pragma unroll
    for (int it = 0; it < 3; it++) {
      int i = it * 256 + tid;
      int t = i >> 6, h = i & 63, hd = h >> 5;
      float afs = 0.f;
#pragma unroll
      for (int s = 0; s < TT; s++) afs += A[hd * TT * TT + t * TT + s] * fss[s];
      float o = ovv[h] * afs + bvs[h];
      float x = o + X[t * TP + h];
      float mu = wsum(x) * (1.0f / 64.0f);
      float d = x - mu;
      float var = wsum(d * d) * (1.0f / 64.0f);
      float v = d * rsqrtf(var + 1e-5f) * g1s[h] + b1s[h];
      val[((size_t)(b * TT + t) * NN + n) * HHID + h] = __float2bfloat16(v);
    }
    __syncthreads();
  }
}

__global__ __launch_bounds__(256, 4) void ffn_kernel(
    const bf16* __restrict__ val, const float* __restrict__ W1, const float* __restrict__ b1,
    const float* __restrict__ W2, const float* __restrict__ b2,
    const float* __restrict__ ln2g, const float* __restrict__ ln2b,
    const float* __restrict__ fcW, const float* __restrict__ fcb,
    float* __restrict__ out, int rows_per_block) {
  __shared__ bf16 W1s[4096], W2s[4096];
  __shared__ float b1s[64], b2s[64], g2s[64], bb2[64], fcs[64];
  __shared__ float vrow[256], grow[256];
  int tid = threadIdx.x;
  for (int i = tid; i < 4096; i += 256) {
    W1s[i] = __float2bfloat16(W1[i]);
    W2s[i] = __float2bfloat16(W2[i]);
  }
  if (tid < 64) {
    b1s[tid] = b1[tid]; b2s[tid] = b2[tid];
    g2s[tid] = ln2g[tid]; bb2[tid] = ln2b[tid]; fcs[tid] = fcW[tid];
  }
  __syncthreads();
  float fcbv = fcb[0];
  int rl = tid >> 6, h = tid & 63;
  for (int c = 0; c < rows_per_block; c += 4) {
    int r = blockIdx.x * rows_per_block + c + rl;
    float x = B2F(val[(size_t)r * 64 + h]);
    vrow[rl * 64 + h] = x;
    float gacc = b1s[h];
#pragma unroll 8
    for (int j = 0; j < 64; j++) gacc += vrow[rl * 64 + j] * B2F(W1s[j * 64 + h]);
    gacc = fmaxf(gacc, 0.0f);
    grow[rl * 64 + h] = gacc;
    float f = b2s[h];
#pragma unroll 8
    for (int j = 0; j < 64; j++) f += grow[rl * 64 + j] * B2F(W2s[j * 64 + h]);
    float y = f + x;
    float mu = wsum(y) * (1.0f / 64.0f);
    float d = y - mu;
    float var = wsum(d * d) * (1.0f / 64.0f);
    float oh = d * rsqrtf(var + 1e-5f) * g2s[h] + bb2[h];
    float contrib = wsum(oh * fcs[h]);
    if (h == 0) out[r] = contrib + fcbv;
  }
}

extern "C" void kernel_launch(void* const* d_in, const int* in_sizes, int n_in,
                              void* d_out, int out_size, void* d_ws, size_t ws_size,
                              hipStream_t stream) {
  const float* src = (const float*)d_in[0];
  const float* emb = (const float*)d_in[2];
  const float* gwp[2] = {(const float*)d_in[3], (const float*)d_in[7]};
  const float* gbp[2] = {(const float*)d_in[4], (const float*)d_in[8]};
  const float* uwp[2] = {(const float*)d_in[5], (const float*)d_in[9]};
  const float* ubp[2] = {(const float*)d_in[6], (const float*)d_in[10]};
  const float* hypW = (const float*)d_in[11];
  const float* hypb = (const float*)d_in[12];
  const float *Wq, *Wk, *Wv, *ffW1, *ffW2, *bq, *bk, *bv, *ffb1, *ffb2;
  const float *ln1g, *ln1b, *ln2g, *ln2b, *fcW, *fcb;
  if (in_sizes[14] == 4096) {  // setup_inputs() dict order
    Wq = (const float*)d_in[13]; Wk = (const float*)d_in[14]; Wv = (const float*)d_in[15];
    ffW1 = (const float*)d_in[16]; ffW2 = (const float*)d_in[17];
    bq = (const float*)d_in[18]; bk = (const float*)d_in[19]; bv = (const float*)d_in[20];
    ffb1 = (const float*)d_in[21]; ffb2 = (const float*)d_in[22];
    ln1g = (const float*)d_in[23]; ln1b = (const float*)d_in[24];
    ln2g = (const float*)d_in[25]; ln2b = (const float*)d_in[26];
    fcW = (const float*)d_in[27]; fcb = (const float*)d_in[28];
  } else {
    Wq = (const float*)d_in[13]; bq = (const float*)d_in[14];
    Wk = (const float*)d_in[15]; bk = (const float*)d_in[16];
    Wv = (const float*)d_in[17]; bv = (const float*)d_in[18];
    ln1g = (const float*)d_in[19]; ln1b = (const float*)d_in[20];
    ffW1 = (const float*)d_in[21]; ffb1 = (const float*)d_in[22];
    ffW2 = (const float*)d_in[23]; ffb2 = (const float*)d_in[24];
    ln2g = (const float*)d_in[25]; ln2b = (const float*)d_in[26];
    fcW = (const float*)d_in[27]; fcb = (const float*)d_in[28];
  }
  float* outp = (float*)d_out;

  char* ws = (char*)d_ws;
  size_t off = 0;
  auto alloc = [&](size_t bytes) {
    void* p = ws + off;
    off += (bytes + 255) & ~(size_t)255;
    return p;
  };
  bf16* adjb = (bf16*)alloc((size_t)512 * 512 * 2);
  bf16* gWb = (bf16*)alloc((size_t)512 * 32768 * 2);   // gate Wt: layer1 256*128, layer0 160*128
  bf16* uWb = (bf16*)alloc((size_t)512 * 16384 * 2);   // upd Wt: layer1 256*64, layer0 160*64
  float* gb = (float*)alloc((size_t)512 * 128 * 4);
  float* ub = (float*)alloc((size_t)512 * 64 * 4);
  bf16* xin0 = (bf16*)alloc((size_t)12 * 512 * 32 * 2 * 2);
  bf16* x0 = (bf16*)alloc((size_t)12 * 512 * 32 * 64 * 2);   // 24 MiB (layer1 in-place)
  bf16* xd0 = (bf16*)alloc((size_t)12 * 512 * 32 * 2 * 2);
  bf16* xdL1 = (bf16*)alloc((size_t)512 * 32 * 64 * 2);
  float* state = (float*)alloc((size_t)512 * 32 * 64 * 4);
  bf16* sb = (bf16*)alloc((size_t)512 * 32 * 64 * 2);
  bf16* sdiff = (bf16*)alloc((size_t)512 * 32 * 64 * 2);
  bf16* zs = (bf16*)alloc((size_t)512 * 32 * 64 * 2);
  bf16* zsdiff = (bf16*)alloc((size_t)512 * 32 * 64 * 2);
  bf16* rbuf = (bf16*)alloc((size_t)512 * 32 * 64 * 2);
  float* PW = (float*)alloc((size_t)16 * 48 * 4);
  float* fsb = (float*)alloc((size_t)512 * 12 * 4);
  bf16* val = gWb;  // weight region dead after recurrence

  adj_kernel<<<512, 256, 0, stream>>>(emb, adjb);
  pw_kernel<<<dim3(48, 16), 256, 0, stream>>>(uwp[1], hypW, PW);
  fs_kernel<<<24, 256, 0, stream>>>(emb, PW, hypb, fsb);
  cvt_src_kernel<<<1536, 256, 0, stream>>>(src, xin0);

  int occ0 = 0, occ1 = 0;
  hipOccupancyMaxActiveBlocksPerMultiprocessor(&occ0, recur_kernel<2>, 256, 0);
  hipOccupancyMaxActiveBlocksPerMultiprocessor(&occ1, recur_kernel<64>, 256, 0);

  for (int l = 0; l < 2; l++) {
    int C = (l == 0) ? 2 : 64;
    int KC = 2 * (C + 64);
    int KCP = (KC + 31) & ~31;  // 160 or 256
    int JG = KC * 128, JU = KC * 64;
    if (KCP != KC) {  // zero pad region (layer0)
      zero_f32_kernel<<<(512 * KCP * 128 / 2 + 255) / 256, 256, 0, stream>>>(
          (float*)gWb, 512 * KCP * 128 / 2);
      zero_f32_kernel<<<(512 * KCP * 64 / 2 + 255) / 256, 256, 0, stream>>>(
          (float*)uWb, 512 * KCP * 64 / 2);
    }
    wgen_t_kernel<<<dim3((JG + 255) / 256, 4), 256, 0, stream>>>(gwp[l], emb, gWb, JG, 7, KCP);
    wgen_t_kernel<<<dim3((JU + 255) / 256, 4), 256, 0, stream>>>(uwp[l], emb, uWb, JU, 6, KCP);
    wgen_kernel<<<dim3(1, 4), 256, 0, stream>>>(gbp[l], emb, gb, 128);
    wgen_kernel<<<dim3(1, 4), 256, 0, stream>>>(ubp[l], emb, ub, 64);

    const bf16* xin = (l == 0) ? xin0 : x0;
    bf16* xd = (l == 0) ? xd0 : xdL1;
    int occ = (l == 0) ? occ0 : occ1;
    int grid = (occ >= 2) ? 512 : (occ == 1 ? 256 : 0);
    hipError_t ce = hipErrorInvalidValue;
    if (grid > 0) {
      void* args[14];
      args[0] = &adjb; args[1] = &xin; args[2] = &gWb; args[3] = &gb;
      args[4] = &uWb; args[5] = &ub; args[6] = &state; args[7] = &sb;
      args[8] = &sdiff; args[9] = &zs; args[10] = &zsdiff; args[11] = &rbuf;
      args[12] = &xd; args[13] = &x0;
      if (l == 0)
        ce = hipLaunchCooperativeKernel(reinterpret_cast<void*>(recur_kernel<2>),
                                        dim3(grid), dim3(256), args, 0, stream);
      else
        ce = hipLaunchCooperativeKernel(reinterpret_cast<void*>(recur_kernel<64>),
                                        dim3(grid), dim3(256), args, 0, stream);
    }
    if (ce != hipSuccess) {
      (void)hipGetLastError();
      // ---- fallback: per-phase kernels (same device functions) ----
      zero_f32_kernel<<<4096, 256, 0, stream>>>(state, 512 * 32 * 64);
      zero_f32_kernel<<<2048, 256, 0, stream>>>((float*)sb, 512 * 32 * 64 / 2);
      if (l == 0) diffuse0_kernel<<<96, 256, 0, stream>>>(adjb, xin, xd);
      for (int t = 0; t < 12; t++) {
        const bf16* xt = xin + (size_t)t * 512 * 32 * C;
        const bf16* xdt = (l == 0) ? (xd + (size_t)t * 512 * 32 * C) : xd;
        bf16* xo = x0 + (size_t)t * 512 * 32 * 64;
        if (l == 1) diffuse1_kernel<<<256, 256, 0, stream>>>(adjb, xt, xd);
        diffuse1_kernel<<<256, 256, 0, stream>>>(adjb, sb, sdiff);
        if (l == 0)
          gate_wrap<2><<<512, 256, 0, stream>>>(xt, xdt, sb, sdiff, gWb, gb, state, zs, rbuf);
        else
          gate_wrap<64><<<512, 256, 0, stream>>>(xt, xdt, sb, sdiff, gWb, gb, state, zs, rbuf);
        diffuse1_kernel<<<256, 256, 0, stream>>>(adjb, zs, zsdiff);
        if (l == 0)
          upd_wrap<2><<<512, 256, 0, stream>>>(xt, xdt, zs, zsdiff, uWb, ub, state, sb, rbuf, xo);
        else
          upd_wrap<64><<<512, 256, 0, stream>>>(xt, xdt, zs, zsdiff, uWb, ub, state, sb, rbuf, xo);
      }
    }
  }

  attn1_kernel<<<2048, 256, 0, stream>>>(x0, fsb, Wq, bq, Wk, bk, Wv, bv, ln1g, ln1b, val);
  ffn_kernel<<<2048, 256, 0, stream>>>(val, ffW1, ffb1, ffW2, ffb2, ln2g, ln2b, fcW, fcb,
                                       outp, 96);
}

// Round 11
// 2404.731 us; speedup vs baseline: 3.1581x; 3.1581x over previous
//
#include <hip/hip_runtime.h>
#include <hip/hip_bf16.h>
#include <hip/hip_cooperative_groups.h>

// MAGCRN on MI355X — round 10: REGISTER-RESIDENT WEIGHTS.
//  * Round-10 counters: recur<64> fetched 533MB/dispatch at ~200 GB/s —
//    latency-bound weight re-streaming (48MB of per-node weights x 12 steps;
//    grid.sync fences defeat cache residency).
//  * Each of 512 blocks owns one node; its gate+upd weight fragments are
//    preloaded ONCE into VGPRs (96/lane layer1) and reused all 12 steps.
//    Weight traffic 576MB -> 48MB per layer.
//  * occ<2 -> per-phase fallback (same math, global-weight path).

namespace cg = cooperative_groups;

using bf16 = __hip_bfloat16;
#define B2F(x) __bfloat162float(x)

#define NN 512
#define BBATCH 32
#define HHID 64
#define TT 12
#define EE 16

typedef __attribute__((ext_vector_type(4))) float f32x4;
typedef __attribute__((ext_vector_type(8))) short bf16x8;

__device__ inline float wsum(float x) {
#pragma unroll
  for (int off = 32; off > 0; off >>= 1) x += __shfl_xor(x, off, 64);
  return x;
}

__global__ __launch_bounds__(256) void zero_f32_kernel(float* __restrict__ p, int n) {
  int i = blockIdx.x * 256 + threadIdx.x;
  if (i < n) p[i] = 0.0f;
}

// ---------------- setup kernels ----------------

__global__ __launch_bounds__(256) void adj_kernel(const float* __restrict__ emb,
                                                  bf16* __restrict__ adjb) {
  __shared__ float embAll[NN * EE];
  __shared__ float red[256];
  int tid = threadIdx.x, n = blockIdx.x;
  for (int i = tid; i < NN * EE; i += 256) embAll[i] = emb[i];
  __syncthreads();
  float v[2];
#pragma unroll
  for (int j = 0; j < 2; j++) {
    int m = tid + j * 256;
    float s = 0.f;
#pragma unroll
    for (int e = 0; e < EE; e++) s += embAll[n * EE + e] * embAll[m * EE + e];
    v[j] = fmaxf(s, 0.0f);
  }
  float mx = fmaxf(v[0], v[1]);
  red[tid] = mx; __syncthreads();
  for (int s = 128; s > 0; s >>= 1) { if (tid < s) red[tid] = fmaxf(red[tid], red[tid + s]); __syncthreads(); }
  mx = red[0]; __syncthreads();
  float e0 = expf(v[0] - mx), e1 = expf(v[1] - mx);
  red[tid] = e0 + e1; __syncthreads();
  for (int s = 128; s > 0; s >>= 1) { if (tid < s) red[tid] += red[tid + s]; __syncthreads(); }
  float inv = 1.0f / red[0];
  adjb[n * NN + tid] = __float2bfloat16(e0 * inv);
  adjb[n * NN + tid + 256] = __float2bfloat16(e1 * inv);
}

// bias generator: out[n][j] = sum_e emb[n][e] * pool[e][j]
__global__ __launch_bounds__(256) void wgen_kernel(const float* __restrict__ pool,
                                                   const float* __restrict__ emb,
                                                   float* __restrict__ out, int J) {
  __shared__ float embL[128 * EE];
  int tid = threadIdx.x;
  int n0 = blockIdx.y * 128;
  for (int i = tid; i < 128 * EE; i += 256) embL[i] = emb[n0 * EE + i];
  __syncthreads();
  int j = blockIdx.x * 256 + tid;
  if (j >= J) return;
  float pw[EE];
#pragma unroll
  for (int e = 0; e < EE; e++) pw[e] = pool[e * J + j];
#pragma unroll 4
  for (int nn = 0; nn < 128; nn++) {
    float s = 0.f;
#pragma unroll
    for (int e = 0; e < EE; e++) s += embL[nn * EE + e] * pw[e];
    out[(size_t)(n0 + nn) * J + j] = s;
  }
}

// transposed weight generator: out[n][o*KCP + kc], j = kc*O + o
__global__ __launch_bounds__(256) void wgen_t_kernel(const float* __restrict__ pool,
                                                     const float* __restrict__ emb,
                                                     bf16* __restrict__ out, int J,
                                                     int lgO, int KCP) {
  __shared__ float embL[128 * EE];
  int tid = threadIdx.x;
  int n0 = blockIdx.y * 128;
  for (int i = tid; i < 128 * EE; i += 256) embL[i] = emb[n0 * EE + i];
  __syncthreads();
  int j = blockIdx.x * 256 + tid;
  if (j >= J) return;
  int O = 1 << lgO;
  int kc = j >> lgO, o = j & (O - 1);
  float pw[EE];
#pragma unroll
  for (int e = 0; e < EE; e++) pw[e] = pool[e * J + j];
  size_t SN = (size_t)KCP << lgO;
#pragma unroll 4
  for (int nn = 0; nn < 128; nn++) {
    float s = 0.f;
#pragma unroll
    for (int e = 0; e < EE; e++) s += embL[nn * EE + e] * pw[e];
    out[(size_t)(n0 + nn) * SN + (size_t)o * KCP + kc] = __float2bfloat16(s);
  }
}

__global__ __launch_bounds__(256) void pw_kernel(const float* __restrict__ upool,
                                                 const float* __restrict__ hypW,
                                                 float* __restrict__ PW) {
  __shared__ float red[256];
  int j = blockIdx.x, e = blockIdx.y, tid = threadIdx.x;
  float s = 0.f;
#pragma unroll 4
  for (int p = tid; p < 16384; p += 256) s += upool[e * 16384 + p] * hypW[p * 48 + j];
  red[tid] = s; __syncthreads();
  for (int t = 128; t > 0; t >>= 1) { if (tid < t) red[tid] += red[tid + t]; __syncthreads(); }
  if (tid == 0) PW[e * 48 + j] = red[0];
}

__global__ __launch_bounds__(256) void fs_kernel(const float* __restrict__ emb,
                                                 const float* __restrict__ PW,
                                                 const float* __restrict__ hypb,
                                                 float* __restrict__ fs) {
  int id = blockIdx.x * 256 + threadIdx.x;
  if (id >= NN * TT) return;
  int n = id / TT, t = id % TT;
  float s = 0.f;
#pragma unroll
  for (int f = 0; f < 4; f++) {
    int j = t * 4 + f;
    float h = hypb[j];
#pragma unroll
    for (int e = 0; e < EE; e++) h += emb[n * EE + e] * PW[e * 48 + j];
    s += h;
  }
  fs[id] = s;
}

__global__ __launch_bounds__(256) void cvt_src_kernel(const float* __restrict__ src,
                                                      bf16* __restrict__ x) {
  int id = blockIdx.x * 256 + threadIdx.x;  // < 393216
  int c = id & 1, b = (id >> 1) & 31, n = (id >> 6) & 511, t = id >> 15;
  x[id] = __float2bfloat16(src[((b * TT + t) * NN + n) * 2 + c]);
}

// ---------------- shared device functions ----------------

// One 64n x 64q diffusion tile via MFMA 16x16x32 (proven structure).
__device__ inline void diffuse_tile(const bf16* __restrict__ adjb,
                                    const bf16* __restrict__ X, bf16* __restrict__ Y,
                                    int Q, int n0, int q0, char* smraw, int tid) {
  constexpr int LP = 66;
  unsigned short* xs = (unsigned short*)smraw;  // [64][66]
  int w = tid >> 6, lane = tid & 63;
  int col = lane & 15, quad = lane >> 4;
  f32x4 acc[4];
#pragma unroll
  for (int ct = 0; ct < 4; ct++) acc[ct] = (f32x4){0.f, 0.f, 0.f, 0.f};
  const bf16* arow = adjb + (size_t)(n0 + w * 16 + col) * NN;
  for (int c = 0; c < 8; c++) {
    __syncthreads();
#pragma unroll
    for (int i0 = 0; i0 < 2; i0++) {
      int i = i0 * 256 + tid;
      int row = i >> 3, seg = i & 7;
      uint4 v = *(const uint4*)(X + (size_t)(c * 64 + row) * Q + q0 + seg * 8);
      unsigned int* dst = (unsigned int*)&xs[row * LP + seg * 8];
      dst[0] = v.x; dst[1] = v.y; dst[2] = v.z; dst[3] = v.w;
    }
    __syncthreads();
#pragma unroll
    for (int ki = 0; ki < 2; ki++) {
      bf16x8 a = *(const bf16x8*)(arow + c * 64 + ki * 32 + quad * 8);
#pragma unroll
      for (int ct = 0; ct < 4; ct++) {
        bf16x8 b;
#pragma unroll
        for (int j = 0; j < 8; j++)
          b[j] = (short)xs[(ki * 32 + quad * 8 + j) * LP + ct * 16 + col];
        acc[ct] = __builtin_amdgcn_mfma_f32_16x16x32_bf16(a, b, acc[ct], 0, 0, 0);
      }
    }
  }
#pragma unroll
  for (int ct = 0; ct < 4; ct++) {
#pragma unroll
    for (int r = 0; r < 4; r++) {
      int row = n0 + w * 16 + quad * 4 + r;
      Y[(size_t)row * Q + q0 + ct * 16 + col] = __float2bfloat16(acc[ct][r]);
    }
  }
}

// Stage A-operand (concat features, bf16) into LDS [32][KCP+8].
template <int C>
__device__ inline void stage_A(int n, int tid, unsigned short* xinb,
    const bf16* __restrict__ xt, const bf16* __restrict__ xd,
    const bf16* __restrict__ sa, const bf16* __restrict__ sad) {
  constexpr int cc = C + HHID, KC = 2 * cc, KCP = (KC + 31) & ~31, PIT = KCP + 8;
  __syncthreads();  // guard LDS reuse
  for (int i = tid; i < 32 * KCP; i += 256) {
    int b = i / KCP, kc = i - b * KCP;
    unsigned short v = 0;
    if (kc < C)            v = *(const unsigned short*)&xt[(n * 32 + b) * C + kc];
    else if (kc < cc)      v = *(const unsigned short*)&sa[(n * 32 + b) * HHID + kc - C];
    else if (kc < cc + C)  v = *(const unsigned short*)&xd[(n * 32 + b) * C + kc - cc];
    else if (kc < KC)      v = *(const unsigned short*)&sad[(n * 32 + b) * HHID + kc - cc - C];
    xinb[b * PIT + kc] = v;
  }
  __syncthreads();
}

// Gate epilogue shared by both weight paths.
template <int C>
__device__ inline void gate_epilogue(int n, int w, int col, int quad,
    f32x4 acc[2][2], const float* __restrict__ gb, const float* __restrict__ state,
    bf16* __restrict__ zs, bf16* __restrict__ rbuf) {
#pragma unroll
  for (int i = 0; i < 2; i++) {
    int o = (w + i * 4) * 16 + col;
    float bv = gb[n * 128 + o];
#pragma unroll
    for (int mt = 0; mt < 2; mt++)
#pragma unroll
      for (int r = 0; r < 4; r++) {
        int m = mt * 16 + quad * 4 + r;
        float zr = 1.0f / (1.0f + expf(-(acc[i][mt][r] + bv)));
        int idx = (n * 32 + m) * HHID + (o & 63);
        if (o < HHID) zs[idx] = __float2bfloat16(zr * state[idx]);
        else          rbuf[idx] = __float2bfloat16(zr);
      }
  }
}

template <int C>
__device__ inline void upd_epilogue(int n, int w, int col, int quad,
    f32x4 acc[2], const float* __restrict__ ub, float* __restrict__ state,
    bf16* __restrict__ sb, const bf16* __restrict__ rbuf, bf16* __restrict__ xo) {
  int o = w * 16 + col;
  float bv = ub[n * 64 + o];
#pragma unroll
  for (int mt = 0; mt < 2; mt++)
#pragma unroll
    for (int r = 0; r < 4; r++) {
      int m = mt * 16 + quad * 4 + r;
      int idx = (n * 32 + m) * HHID + o;
      float hc = tanhf(acc[mt][r] + bv);
      float rr = B2F(rbuf[idx]);
      float st = state[idx];
      float h = rr * st + (1.0f - rr) * hc;
      state[idx] = h;
      bf16 hb = __float2bfloat16(h);
      sb[idx] = hb;
      xo[idx] = hb;
    }
}

// Global-weight gate/upd (fallback path).
template <int C>
__device__ inline void gate_mfma(int n, int tid, const unsigned short* xinb,
    const bf16* __restrict__ gWt, const float* __restrict__ gb,
    const float* __restrict__ state, bf16* __restrict__ zs, bf16* __restrict__ rbuf) {
  constexpr int KC = 2 * (C + HHID), KCP = (KC + 31) & ~31, PIT = KCP + 8;
  int w = tid >> 6, lane = tid & 63, col = lane & 15, quad = lane >> 4;
  f32x4 acc[2][2];
#pragma unroll
  for (int i = 0; i < 2; i++)
#pragma unroll
    for (int mt = 0; mt < 2; mt++) acc[i][mt] = (f32x4){0.f, 0.f, 0.f, 0.f};
  const bf16* Wn = gWt + (size_t)n * KCP * 128;
#pragma unroll 2
  for (int k0 = 0; k0 < KCP; k0 += 32) {
    int ko = k0 + quad * 8;
    bf16x8 a0 = *(const bf16x8*)&xinb[col * PIT + ko];
    bf16x8 a1 = *(const bf16x8*)&xinb[(16 + col) * PIT + ko];
#pragma unroll
    for (int i = 0; i < 2; i++) {
      int o = (w + i * 4) * 16 + col;
      bf16x8 bf = *(const bf16x8*)(Wn + (size_t)o * KCP + ko);
      acc[i][0] = __builtin_amdgcn_mfma_f32_16x16x32_bf16(a0, bf, acc[i][0], 0, 0, 0);
      acc[i][1] = __builtin_amdgcn_mfma_f32_16x16x32_bf16(a1, bf, acc[i][1], 0, 0, 0);
    }
  }
  gate_epilogue<C>(n, w, col, quad, acc, gb, state, zs, rbuf);
}

template <int C>
__device__ inline void upd_mfma(int n, int tid, const unsigned short* xinb,
    const bf16* __restrict__ uWt, const float* __restrict__ ub,
    float* __restrict__ state, bf16* __restrict__ sb,
    const bf16* __restrict__ rbuf, bf16* __restrict__ xo) {
  constexpr int KC = 2 * (C + HHID), KCP = (KC + 31) & ~31, PIT = KCP + 8;
  int w = tid >> 6, lane = tid & 63, col = lane & 15, quad = lane >> 4;
  f32x4 acc[2];
  acc[0] = (f32x4){0.f, 0.f, 0.f, 0.f};
  acc[1] = (f32x4){0.f, 0.f, 0.f, 0.f};
  const bf16* Wn = uWt + (size_t)n * KCP * 64;
  int o = w * 16 + col;
#pragma unroll 2
  for (int k0 = 0; k0 < KCP; k0 += 32) {
    int ko = k0 + quad * 8;
    bf16x8 a0 = *(const bf16x8*)&xinb[col * PIT + ko];
    bf16x8 a1 = *(const bf16x8*)&xinb[(16 + col) * PIT + ko];
    bf16x8 bf = *(const bf16x8*)(Wn + (size_t)o * KCP + ko);
    acc[0] = __builtin_amdgcn_mfma_f32_16x16x32_bf16(a0, bf, acc[0], 0, 0, 0);
    acc[1] = __builtin_amdgcn_mfma_f32_16x16x32_bf16(a1, bf, acc[1], 0, 0, 0);
  }
  upd_epilogue<C>(n, w, col, quad, acc, ub, state, sb, rbuf, xo);
}

// ---------------- cooperative recurrence (512 blocks, weights in VGPRs) -----

template <int C>
__global__ __launch_bounds__(256, 2) void recur_kernel(
    const bf16* __restrict__ adjb, const bf16* __restrict__ xin,
    const bf16* __restrict__ gWt, const float* __restrict__ gb,
    const bf16* __restrict__ uWt, const float* __restrict__ ub,
    float* __restrict__ state, bf16* __restrict__ sb,
    bf16* __restrict__ sdiff, bf16* __restrict__ zs, bf16* __restrict__ zsdiff,
    bf16* __restrict__ rbuf, bf16* __restrict__ xd, bf16* __restrict__ xout) {
  constexpr int KC = 2 * (C + HHID), KCP = (KC + 31) & ~31, PIT = KCP + 8;
  constexpr int NK = KCP / 32;          // 8 (layer1) or 5 (layer0)
  constexpr int QX = 32 * C;
  constexpr int SMB = (32 * PIT * 2 > 8448) ? 32 * PIT * 2 : 8448;
  __shared__ __align__(16) char smraw[SMB];
  unsigned short* xinb = (unsigned short*)smraw;
  cg::grid_group grid = cg::this_grid();
  int bid = blockIdx.x, tid = threadIdx.x;   // grid is exactly 512 blocks
  int w = tid >> 6, lane = tid & 63, col = lane & 15, quad = lane >> 4;

  // --- preload this node's weights into registers (once) ---
  bf16x8 fg[2 * NK];
  {
    const bf16* Wn = gWt + (size_t)bid * KCP * 128;
#pragma unroll
    for (int i = 0; i < 2; i++) {
      int o = (w + i * 4) * 16 + col;
#pragma unroll
      for (int kk = 0; kk < NK; kk++)
        fg[i * NK + kk] = *(const bf16x8*)(Wn + (size_t)o * KCP + kk * 32 + quad * 8);
    }
  }
  bf16x8 fu[NK];
  {
    const bf16* Wn = uWt + (size_t)bid * KCP * 64;
    int o = w * 16 + col;
#pragma unroll
    for (int kk = 0; kk < NK; kk++)
      fu[kk] = *(const bf16x8*)(Wn + (size_t)o * KCP + kk * 32 + quad * 8);
  }

  for (int i = bid * 256 + tid; i < NN * 32 * HHID; i += 512 * 256) {
    state[i] = 0.f;
    sb[i] = __float2bfloat16(0.f);
  }
  if (C == 2 && bid < 96) {  // layer0: all-t input diffusion (Q=64, 96 tiles)
    int t = bid >> 3, nn0 = (bid & 7) * 64;
    diffuse_tile(adjb, xin + (size_t)t * NN * QX, xd + (size_t)t * NN * QX,
                 QX, nn0, 0, smraw, tid);
  }
  grid.sync();

  for (int t = 0; t < TT; t++) {
    const bf16* xt = xin + (size_t)t * NN * QX;
    const bf16* xdt = (C == 2) ? (xd + (size_t)t * NN * QX) : xd;
    bf16* xo = xout + (size_t)t * NN * 32 * HHID;
    // P1: sdiff = adj @ sb (blocks 0..255); layer1 also xdiff (blocks 256..511)
    if (bid < 256) {
      diffuse_tile(adjb, sb, sdiff, 2048, (bid >> 5) * 64, (bid & 31) * 64, smraw, tid);
    } else if (C == 64) {
      int b2 = bid - 256;
      diffuse_tile(adjb, xt, xd, 2048, (b2 >> 5) * 64, (b2 & 31) * 64, smraw, tid);
    }
    grid.sync();
    // P2: gate gconv with register-resident weights
    {
      stage_A<C>(bid, tid, xinb, xt, xdt, sb, sdiff);
      f32x4 acc[2][2];
#pragma unroll
      for (int i = 0; i < 2; i++)
#pragma unroll
        for (int mt = 0; mt < 2; mt++) acc[i][mt] = (f32x4){0.f, 0.f, 0.f, 0.f};
#pragma unroll
      for (int kk = 0; kk < NK; kk++) {
        int ko = kk * 32 + quad * 8;
        bf16x8 a0 = *(const bf16x8*)&xinb[col * PIT + ko];
        bf16x8 a1 = *(const bf16x8*)&xinb[(16 + col) * PIT + ko];
#pragma unroll
        for (int i = 0; i < 2; i++) {
          acc[i][0] = __builtin_amdgcn_mfma_f32_16x16x32_bf16(a0, fg[i * NK + kk], acc[i][0], 0, 0, 0);
          acc[i][1] = __builtin_amdgcn_mfma_f32_16x16x32_bf16(a1, fg[i * NK + kk], acc[i][1], 0, 0, 0);
        }
      }
      gate_epilogue<C>(bid, w, col, quad, acc, gb, state, zs, rbuf);
    }
    grid.sync();
    // P3: zsdiff = adj @ zs (blocks 0..255)
    if (bid < 256)
      diffuse_tile(adjb, zs, zsdiff, 2048, (bid >> 5) * 64, (bid & 31) * 64, smraw, tid);
    grid.sync();
    // P4: update gconv with register-resident weights -> state, sb, xout[t]
    {
      stage_A<C>(bid, tid, xinb, xt, xdt, zs, zsdiff);
      f32x4 acc[2];
      acc[0] = (f32x4){0.f, 0.f, 0.f, 0.f};
      acc[1] = (f32x4){0.f, 0.f, 0.f, 0.f};
#pragma unroll
      for (int kk = 0; kk < NK; kk++) {
        int ko = kk * 32 + quad * 8;
        bf16x8 a0 = *(const bf16x8*)&xinb[col * PIT + ko];
        bf16x8 a1 = *(const bf16x8*)&xinb[(16 + col) * PIT + ko];
        acc[0] = __builtin_amdgcn_mfma_f32_16x16x32_bf16(a0, fu[kk], acc[0], 0, 0, 0);
        acc[1] = __builtin_amdgcn_mfma_f32_16x16x32_bf16(a1, fu[kk], acc[1], 0, 0, 0);
      }
      upd_epilogue<C>(bid, w, col, quad, acc, ub, state, sb, rbuf, xo);
    }
    grid.sync();
  }
}

// ---------------- fallback per-phase kernels (same math) ----------------

__global__ __launch_bounds__(256, 2) void diffuse0_kernel(const bf16* __restrict__ adjb,
                                                          const bf16* __restrict__ X,
                                                          bf16* __restrict__ Y) {
  __shared__ __align__(16) char smraw[8448];
  int bid = blockIdx.x;  // 96
  int t = bid >> 3, n0 = (bid & 7) * 64;
  diffuse_tile(adjb, X + (size_t)t * NN * 64, Y + (size_t)t * NN * 64, 64, n0, 0,
               smraw, threadIdx.x);
}

__global__ __launch_bounds__(256, 2) void diffuse1_kernel(const bf16* __restrict__ adjb,
                                                          const bf16* __restrict__ X,
                                                          bf16* __restrict__ Y) {
  __shared__ __align__(16) char smraw[8448];
  int bid = blockIdx.x;  // 256
  diffuse_tile(adjb, X, Y, 2048, (bid >> 5) * 64, (bid & 31) * 64, smraw, threadIdx.x);
}

template <int C>
__global__ __launch_bounds__(256, 2) void gate_wrap(
    const bf16* xt, const bf16* xdt, const bf16* sa, const bf16* sad,
    const bf16* gWt, const float* gb, const float* state, bf16* zs, bf16* rbuf) {
  constexpr int KC = 2 * (C + HHID), KCP = (KC + 31) & ~31, PIT = KCP + 8;
  __shared__ __align__(16) unsigned short xinb[32 * PIT];
  stage_A<C>(blockIdx.x, threadIdx.x, xinb, xt, xdt, sa, sad);
  gate_mfma<C>(blockIdx.x, threadIdx.x, xinb, gWt, gb, state, zs, rbuf);
}

template <int C>
__global__ __launch_bounds__(256, 2) void upd_wrap(
    const bf16* xt, const bf16* xdt, const bf16* sa, const bf16* sad,
    const bf16* uWt, const float* ub, float* state, bf16* sb,
    const bf16* rbuf, bf16* xo) {
  constexpr int KC = 2 * (C + HHID), KCP = (KC + 31) & ~31, PIT = KCP + 8;
  __shared__ __align__(16) unsigned short xinb[32 * PIT];
  stage_A<C>(blockIdx.x, threadIdx.x, xinb, xt, xdt, sa, sad);
  upd_mfma<C>(blockIdx.x, threadIdx.x, xinb, uWt, ub, state, sb, rbuf, xo);
}

// ---------------- epilogue kernels (unchanged, passing) ----------------

#define TP 68  // padded fp32 row stride (conflict-free)

__global__ __launch_bounds__(256, 4) void attn1_kernel(
    const bf16* __restrict__ x1, const float* __restrict__ fsb,
    const float* __restrict__ Wq, const float* __restrict__ bq,
    const float* __restrict__ Wk, const float* __restrict__ bk,
    const float* __restrict__ Wv, const float* __restrict__ bv,
    const float* __restrict__ ln1g, const float* __restrict__ ln1b,
    bf16* __restrict__ val) {
  __shared__ bf16 Wq_s[4096], Wk_s[4096], Wv_s[4096];
  __shared__ float X[TT * TP], qs[TT * TP], ks[TT * TP];
  __shared__ float A[2 * TT * TT];
  __shared__ float ovv[64], fss[TT];
  __shared__ float bqs[64], bks[64], bvs[64], g1s[64], b1s[64];
  int tid = threadIdx.x;
  for (int i = tid; i < 4096; i += 256) {
    Wq_s[i] = __float2bfloat16(Wq[i]);
    Wk_s[i] = __float2bfloat16(Wk[i]);
    Wv_s[i] = __float2bfloat16(Wv[i]);
  }
  if (tid < 64) {
    bqs[tid] = bq[tid]; bks[tid] = bk[tid]; bvs[tid] = bv[tid];
    g1s[tid] = ln1g[tid]; b1s[tid] = ln1b[tid];
  }
  __syncthreads();
  for (int g = 0; g < 8; g++) {
    int p = blockIdx.x * 8 + g;
    int b = p >> 9, n = p & 511;
    for (int i = tid; i < TT * 64; i += 256) {
      int t = i >> 6, j = i & 63;
      X[t * TP + j] = B2F(x1[(((size_t)t * NN + n) * BBATCH + b) * HHID + j]);
    }
    if (tid < TT) fss[tid] = fsb[n * TT + tid];
    __syncthreads();
    for (int i = tid; i < TT * 64; i += 256) {
      int t = i >> 6, h = i & 63;
      float aq = bqs[h], ak = bks[h];
#pragma unroll 8
      for (int j = 0; j < 64; j++) {
        float xv = X[t * TP + j];
        aq += xv * B2F(Wq_s[j * 64 + h]);
        ak += xv * B2F(Wk_s[j * 64 + h]);
      }
      qs[t * TP + h] = aq; ks[t * TP + h] = ak;
    }
    if (tid < 64) {
      float s = 0.f;
#pragma unroll 8
      for (int j = 0; j < 64; j++) s += X[11 * TP + j] * B2F(Wv_s[j * 64 + tid]);
      ovv[tid] = s;
    }
    __syncthreads();
    for (int i = tid; i < 2 * TT * TT; i += 256) {
      int hd = i / (TT * TT), ts = i % (TT * TT), t = ts / TT, s = ts % TT;
      float acc = 0.f;
#pragma unroll
      for (int d = 0; d < 32; d++) acc += qs[t * TP + hd * 32 + d] * ks[s * TP + hd * 32 + d];
      A[i] = acc * 0.17677669529663687f;
    }
    __syncthreads();
    if (tid < 2 * TT) {
      int hd = tid / TT, t = tid % TT;
      float* row = &A[hd * TT * TT + t * TT];
      float m = row[0];
      for (int s = 1; s < TT; s++) m = fmaxf(m, row[s]);
      float sm = 0.f;
      for (int s = 0; s < TT; s++) { float e = expf(row[s] - m); row[s] = e; sm += e; }
      float inv = 1.0f / sm;
      for (int s = 0; s < TT; s++) row[s] *= inv;
    }
    __syncthreads();
#pragma unroll
    for (int it = 0; it < 3; it++) {
      int i = it * 256 + tid;
      int t = i >> 6, h = i & 63, hd = h >> 5;
      float afs = 0.f;
#pragma unroll
      for (int s = 0; s < TT; s++) afs += A[hd * TT * TT + t * TT + s] * fss[s];
      float o = ovv[h] * afs + bvs[h];
      float x = o + X[t * TP + h];
      float mu = wsum(x) * (1.0f / 64.0f);
      float d = x - mu;
      float var = wsum(d * d) * (1.0f / 64.0f);
      float v = d * rsqrtf(var + 1e-5f) * g1s[h] + b1s[h];
      val[((size_t)(b * TT + t) * NN + n) * HHID + h] = __float2bfloat16(v);
    }
    __syncthreads();
  }
}

__global__ __launch_bounds__(256, 4) void ffn_kernel(
    const bf16* __restrict__ val, const float* __restrict__ W1, const float* __restrict__ b1,
    const float* __restrict__ W2, const float* __restrict__ b2,
    const float* __restrict__ ln2g, const float* __restrict__ ln2b,
    const float* __restrict__ fcW, const float* __restrict__ fcb,
    float* __restrict__ out, int rows_per_block) {
  __shared__ bf16 W1s[4096], W2s[4096];
  __shared__ float b1s[64], b2s[64], g2s[64], bb2[64], fcs[64];
  __shared__ float vrow[256], grow[256];
  int tid = threadIdx.x;
  for (int i = tid; i < 4096; i += 256) {
    W1s[i] = __float2bfloat16(W1[i]);
    W2s[i] = __float2bfloat16(W2[i]);
  }
  if (tid < 64) {
    b1s[tid] = b1[tid]; b2s[tid] = b2[tid];
    g2s[tid] = ln2g[tid]; bb2[tid] = ln2b[tid]; fcs[tid] = fcW[tid];
  }
  __syncthreads();
  float fcbv = fcb[0];
  int rl = tid >> 6, h = tid & 63;
  for (int c = 0; c < rows_per_block; c += 4) {
    int r = blockIdx.x * rows_per_block + c + rl;
    float x = B2F(val[(size_t)r * 64 + h]);
    vrow[rl * 64 + h] = x;
    float gacc = b1s[h];
#pragma unroll 8
    for (int j = 0; j < 64; j++) gacc += vrow[rl * 64 + j] * B2F(W1s[j * 64 + h]);
    gacc = fmaxf(gacc, 0.0f);
    grow[rl * 64 + h] = gacc;
    float f = b2s[h];
#pragma unroll 8
    for (int j = 0; j < 64; j++) f += grow[rl * 64 + j] * B2F(W2s[j * 64 + h]);
    float y = f + x;
    float mu = wsum(y) * (1.0f / 64.0f);
    float d = y - mu;
    float var = wsum(d * d) * (1.0f / 64.0f);
    float oh = d * rsqrtf(var + 1e-5f) * g2s[h] + bb2[h];
    float contrib = wsum(oh * fcs[h]);
    if (h == 0) out[r] = contrib + fcbv;
  }
}

extern "C" void kernel_launch(void* const* d_in, const int* in_sizes, int n_in,
                              void* d_out, int out_size, void* d_ws, size_t ws_size,
                              hipStream_t stream) {
  const float* src = (const float*)d_in[0];
  const float* emb = (const float*)d_in[2];
  const float* gwp[2] = {(const float*)d_in[3], (const float*)d_in[7]};
  const float* gbp[2] = {(const float*)d_in[4], (const float*)d_in[8]};
  const float* uwp[2] = {(const float*)d_in[5], (const float*)d_in[9]};
  const float* ubp[2] = {(const float*)d_in[6], (const float*)d_in[10]};
  const float* hypW = (const float*)d_in[11];
  const float* hypb = (const float*)d_in[12];
  const float *Wq, *Wk, *Wv, *ffW1, *ffW2, *bq, *bk, *bv, *ffb1, *ffb2;
  const float *ln1g, *ln1b, *ln2g, *ln2b, *fcW, *fcb;
  if (in_sizes[14] == 4096) {  // setup_inputs() dict order
    Wq = (const float*)d_in[13]; Wk = (const float*)d_in[14]; Wv = (const float*)d_in[15];
    ffW1 = (const float*)d_in[16]; ffW2 = (const float*)d_in[17];
    bq = (const float*)d_in[18]; bk = (const float*)d_in[19]; bv = (const float*)d_in[20];
    ffb1 = (const float*)d_in[21]; ffb2 = (const float*)d_in[22];
    ln1g = (const float*)d_in[23]; ln1b = (const float*)d_in[24];
    ln2g = (const float*)d_in[25]; ln2b = (const float*)d_in[26];
    fcW = (const float*)d_in[27]; fcb = (const float*)d_in[28];
  } else {
    Wq = (const float*)d_in[13]; bq = (const float*)d_in[14];
    Wk = (const float*)d_in[15]; bk = (const float*)d_in[16];
    Wv = (const float*)d_in[17]; bv = (const float*)d_in[18];
    ln1g = (const float*)d_in[19]; ln1b = (const float*)d_in[20];
    ffW1 = (const float*)d_in[21]; ffb1 = (const float*)d_in[22];
    ffW2 = (const float*)d_in[23]; ffb2 = (const float*)d_in[24];
    ln2g = (const float*)d_in[25]; ln2b = (const float*)d_in[26];
    fcW = (const float*)d_in[27]; fcb = (const float*)d_in[28];
  }
  float* outp = (float*)d_out;

  char* ws = (char*)d_ws;
  size_t off = 0;
  auto alloc = [&](size_t bytes) {
    void* p = ws + off;
    off += (bytes + 255) & ~(size_t)255;
    return p;
  };
  bf16* adjb = (bf16*)alloc((size_t)512 * 512 * 2);
  bf16* gWb = (bf16*)alloc((size_t)512 * 32768 * 2);
  bf16* uWb = (bf16*)alloc((size_t)512 * 16384 * 2);
  float* gb = (float*)alloc((size_t)512 * 128 * 4);
  float* ub = (float*)alloc((size_t)512 * 64 * 4);
  bf16* xin0 = (bf16*)alloc((size_t)12 * 512 * 32 * 2 * 2);
  bf16* x0 = (bf16*)alloc((size_t)12 * 512 * 32 * 64 * 2);   // 24 MiB (layer1 in-place)
  bf16* xd0 = (bf16*)alloc((size_t)12 * 512 * 32 * 2 * 2);
  bf16* xdL1 = (bf16*)alloc((size_t)512 * 32 * 64 * 2);
  float* state = (float*)alloc((size_t)512 * 32 * 64 * 4);
  bf16* sb = (bf16*)alloc((size_t)512 * 32 * 64 * 2);
  bf16* sdiff = (bf16*)alloc((size_t)512 * 32 * 64 * 2);
  bf16* zs = (bf16*)alloc((size_t)512 * 32 * 64 * 2);
  bf16* zsdiff = (bf16*)alloc((size_t)512 * 32 * 64 * 2);
  bf16* rbuf = (bf16*)alloc((size_t)512 * 32 * 64 * 2);
  float* PW = (float*)alloc((size_t)16 * 48 * 4);
  float* fsb = (float*)alloc((size_t)512 * 12 * 4);
  bf16* val = gWb;  // weight region dead after recurrence

  adj_kernel<<<512, 256, 0, stream>>>(emb, adjb);
  pw_kernel<<<dim3(48, 16), 256, 0, stream>>>(uwp[1], hypW, PW);
  fs_kernel<<<24, 256, 0, stream>>>(emb, PW, hypb, fsb);
  cvt_src_kernel<<<1536, 256, 0, stream>>>(src, xin0);

  int occ0 = 0, occ1 = 0;
  hipOccupancyMaxActiveBlocksPerMultiprocessor(&occ0, recur_kernel<2>, 256, 0);
  hipOccupancyMaxActiveBlocksPerMultiprocessor(&occ1, recur_kernel<64>, 256, 0);

  for (int l = 0; l < 2; l++) {
    int C = (l == 0) ? 2 : 64;
    int KC = 2 * (C + 64);
    int KCP = (KC + 31) & ~31;  // 160 or 256
    int JG = KC * 128, JU = KC * 64;
    if (KCP != KC) {  // zero pad region (layer0)
      zero_f32_kernel<<<(512 * KCP * 128 / 2 + 255) / 256, 256, 0, stream>>>(
          (float*)gWb, 512 * KCP * 128 / 2);
      zero_f32_kernel<<<(512 * KCP * 64 / 2 + 255) / 256, 256, 0, stream>>>(
          (float*)uWb, 512 * KCP * 64 / 2);
    }
    wgen_t_kernel<<<dim3((JG + 255) / 256, 4), 256, 0, stream>>>(gwp[l], emb, gWb, JG, 7, KCP);
    wgen_t_kernel<<<dim3((JU + 255) / 256, 4), 256, 0, stream>>>(uwp[l], emb, uWb, JU, 6, KCP);
    wgen_kernel<<<dim3(1, 4), 256, 0, stream>>>(gbp[l], emb, gb, 128);
    wgen_kernel<<<dim3(1, 4), 256, 0, stream>>>(ubp[l], emb, ub, 64);

    const bf16* xin = (l == 0) ? xin0 : x0;
    bf16* xd = (l == 0) ? xd0 : xdL1;
    int occ = (l == 0) ? occ0 : occ1;
    hipError_t ce = hipErrorInvalidValue;
    if (occ >= 2) {  // kernel requires exactly 512 co-resident blocks
      void* args[14];
      args[0] = &adjb; args[1] = &xin; args[2] = &gWb; args[3] = &gb;
      args[4] = &uWb; args[5] = &ub; args[6] = &state; args[7] = &sb;
      args[8] = &sdiff; args[9] = &zs; args[10] = &zsdiff; args[11] = &rbuf;
      args[12] = &xd; args[13] = &x0;
      if (l == 0)
        ce = hipLaunchCooperativeKernel(reinterpret_cast<void*>(recur_kernel<2>),
                                        dim3(512), dim3(256), args, 0, stream);
      else
        ce = hipLaunchCooperativeKernel(reinterpret_cast<void*>(recur_kernel<64>),
                                        dim3(512), dim3(256), args, 0, stream);
    }
    if (ce != hipSuccess) {
      (void)hipGetLastError();
      // ---- fallback: per-phase kernels (same math) ----
      zero_f32_kernel<<<4096, 256, 0, stream>>>(state, 512 * 32 * 64);
      zero_f32_kernel<<<2048, 256, 0, stream>>>((float*)sb, 512 * 32 * 64 / 2);
      if (l == 0) diffuse0_kernel<<<96, 256, 0, stream>>>(adjb, xin, xd);
      for (int t = 0; t < 12; t++) {
        const bf16* xt = xin + (size_t)t * 512 * 32 * C;
        const bf16* xdt = (l == 0) ? (xd + (size_t)t * 512 * 32 * C) : xd;
        bf16* xo = x0 + (size_t)t * 512 * 32 * 64;
        if (l == 1) diffuse1_kernel<<<256, 256, 0, stream>>>(adjb, xt, xd);
        diffuse1_kernel<<<256, 256, 0, stream>>>(adjb, sb, sdiff);
        if (l == 0)
          gate_wrap<2><<<512, 256, 0, stream>>>(xt, xdt, sb, sdiff, gWb, gb, state, zs, rbuf);
        else
          gate_wrap<64><<<512, 256, 0, stream>>>(xt, xdt, sb, sdiff, gWb, gb, state, zs, rbuf);
        diffuse1_kernel<<<256, 256, 0, stream>>>(adjb, zs, zsdiff);
        if (l == 0)
          upd_wrap<2><<<512, 256, 0, stream>>>(xt, xdt, zs, zsdiff, uWb, ub, state, sb, rbuf, xo);
        else
          upd_wrap<64><<<512, 256, 0, stream>>>(xt, xdt, zs, zsdiff, uWb, ub, state, sb, rbuf, xo);
      }
    }
  }

  attn1_kernel<<<2048, 256, 0, stream>>>(x0, fsb, Wq, bq, Wk, bk, Wv, bv, ln1g, ln1b, val);
  ffn_kernel<<<2048, 256, 0, stream>>>(val, ffW1, ffb1, ffW2, ffb2, ln2g, ln2b, fcW, fcb,
                                       outp, 96);
}